// Round 8
// baseline (474.169 us; speedup 1.0000x reference)
//
#include <hip/hip_runtime.h>
#include <hip/hip_bf16.h>
#include <stdint.h>

#define B_ 4
#define T_ 64
#define L_ 4096
#define D_ 4096
#define REP 4   // profiling: repeat K-loop inside GEMM kernels (identical output)

using bf8   = __attribute__((ext_vector_type(8))) short;   // 8 bf16 (4 VGPRs)
using f32x4 = __attribute__((ext_vector_type(4))) float;   // MFMA accumulator

// round-to-nearest-even fp32 -> bf16 (bit pattern in ushort)
__device__ __forceinline__ unsigned short f2bf(float f) {
    union { float f; unsigned int u; } v;
    v.f = f;
    unsigned int r = v.u + 0x7fffu + ((v.u >> 16) & 1u);
    return (unsigned short)(r >> 16);
}

// XOR swizzle on 16B chunks within a 128B LDS row; same fn on write & read.
__device__ __forceinline__ int swz16(int row, int byteoff) {
    return byteoff ^ (((row ^ (row >> 3)) & 7) << 4);
}

// MFMA fragment read from a [rows][64] bf16 tile (128B row stride).
__device__ __forceinline__ bf8 read_frag(const unsigned short* lds, int row, int kk, int lane) {
    int byte = kk * 64 + ((lane >> 4) << 4);
    int off  = row * 128 + swz16(row, byte);
    return *reinterpret_cast<const bf8*>(reinterpret_cast<const char*>(lds) + off);
}

// ---------------- Kernel 0: Q fp32 -> bf16 once ----------------
__global__ __launch_bounds__(256) void k_qprep(const float* __restrict__ Q,
                                               unsigned short* __restrict__ Qbf) {
    int i = blockIdx.x * 256 + threadIdx.x;          // 65536 float4s
    float4 f = reinterpret_cast<const float4*>(Q)[i];
    ushort4 u;
    u.x = f2bf(f.x); u.y = f2bf(f.y); u.z = f2bf(f.z); u.w = f2bf(f.w);
    reinterpret_cast<ushort4*>(Qbf)[i] = u;
}

// ==================== Kernel 1: scores = Q . mask^T / 64 ====================
// R1-proven structure: grid (L/64, B), 256 thr, 64x64 tile, K-step 64, drain loop.
// REP x identical passes (acc reset per rep) purely to lengthen the dispatch for rocprof.
__global__ __launch_bounds__(256, 1) void k_scores(
    const float* __restrict__ mask, const unsigned short* __restrict__ Qbf,
    float* __restrict__ scores) {
    __shared__ unsigned short lA[2][64 * 64];   // Q tile   [t][k] bf16
    __shared__ unsigned short lB[2][64 * 64];   // mask tile[l][k] bf16
    const int tid  = threadIdx.x;
    const int lane = tid & 63;
    const int wave = tid >> 6;
    const int wm = wave >> 1, wn = wave & 1;
    const int b  = blockIdx.y;
    const int l0 = blockIdx.x * 64;
    const float* __restrict__ Mb = mask + (size_t)b * L_ * D_;

    f32x4 acc[2][2];
    uint4  ra[2];
    float4 rb[4];

    auto loadTiles = [&](int k0) {
#pragma unroll
        for (int s = 0; s < 2; ++s) {
            int slot = tid + s * 256;
            int r = slot >> 3, c = slot & 7;
            ra[s] = *reinterpret_cast<const uint4*>(Qbf + (size_t)r * D_ + k0 + c * 8);
        }
#pragma unroll
        for (int s = 0; s < 4; ++s) {
            int slot = tid + s * 256;
            int r = slot >> 4, c = slot & 15;
            rb[s] = *reinterpret_cast<const float4*>(Mb + (size_t)(l0 + r) * D_ + k0 + c * 4);
        }
    };
    auto writeTiles = [&](int buf) {
#pragma unroll
        for (int s = 0; s < 2; ++s) {
            int slot = tid + s * 256;
            int r = slot >> 3, c = slot & 7;
            int off = r * 128 + swz16(r, c * 16);
            *reinterpret_cast<uint4*>(reinterpret_cast<char*>(lA[buf]) + off) = ra[s];
        }
#pragma unroll
        for (int s = 0; s < 4; ++s) {
            int slot = tid + s * 256;
            int r = slot >> 4, c = slot & 15;
            int off = r * 128 + swz16(r, c * 8);
            ushort4 u;
            u.x = f2bf(rb[s].x); u.y = f2bf(rb[s].y); u.z = f2bf(rb[s].z); u.w = f2bf(rb[s].w);
            *reinterpret_cast<ushort4*>(reinterpret_cast<char*>(lB[buf]) + off) = u;
        }
    };

    const int NT = D_ / 64;
    for (int rep = 0; rep < REP; ++rep) {
#pragma unroll
        for (int mi = 0; mi < 2; ++mi)
#pragma unroll
            for (int nj = 0; nj < 2; ++nj)
                acc[mi][nj] = f32x4{0.f, 0.f, 0.f, 0.f};

        loadTiles(0);
        writeTiles(0);
        __syncthreads();
        for (int kt = 0; kt < NT; ++kt) {
            int cur = kt & 1;
            if (kt + 1 < NT) loadTiles((kt + 1) * 64);
#pragma unroll
            for (int kk = 0; kk < 2; ++kk) {
                bf8 a0 = read_frag(lA[cur], wm * 32 +      (lane & 15), kk, lane);
                bf8 a1 = read_frag(lA[cur], wm * 32 + 16 + (lane & 15), kk, lane);
                bf8 b0 = read_frag(lB[cur], wn * 32 +      (lane & 15), kk, lane);
                bf8 b1 = read_frag(lB[cur], wn * 32 + 16 + (lane & 15), kk, lane);
                acc[0][0] = __builtin_amdgcn_mfma_f32_16x16x32_bf16(a0, b0, acc[0][0], 0, 0, 0);
                acc[0][1] = __builtin_amdgcn_mfma_f32_16x16x32_bf16(a0, b1, acc[0][1], 0, 0, 0);
                acc[1][0] = __builtin_amdgcn_mfma_f32_16x16x32_bf16(a1, b0, acc[1][0], 0, 0, 0);
                acc[1][1] = __builtin_amdgcn_mfma_f32_16x16x32_bf16(a1, b1, acc[1][1], 0, 0, 0);
            }
            if (kt + 1 < NT) writeTiles(cur ^ 1);
            __syncthreads();
        }
    }

    const int rgrp = (lane >> 4) * 4;
    const int cidx = lane & 15;
#pragma unroll
    for (int mi = 0; mi < 2; ++mi)
#pragma unroll
        for (int nj = 0; nj < 2; ++nj)
#pragma unroll
            for (int r = 0; r < 4; ++r) {
                int t = wm * 32 + mi * 16 + rgrp + r;
                int l = l0 + wn * 32 + nj * 16 + cidx;
                scores[((size_t)b * T_ + t) * L_ + l] = acc[mi][nj][r] * 0.015625f;
            }
}

// ---------------- Kernel 2: masked softmax over L, fp32 scores -> bf16 attn ----------------
__global__ __launch_bounds__(256, 4) void k_softmax(
    const float* __restrict__ scores, const int* __restrict__ am,
    unsigned short* __restrict__ attn) {
    const int row  = blockIdx.x;
    const int tid  = threadIdx.x;
    const int lane = tid & 63;
    const int wave = tid >> 6;
    const float* __restrict__ s = scores + (size_t)row * L_;
    const int*   __restrict__ m = am     + (size_t)row * L_;
    __shared__ float redmax[4], redsum[4];

    float v[16];
#pragma unroll
    for (int j = 0; j < 4; ++j) {
        float4 f = *(reinterpret_cast<const float4*>(s) + tid + j * 256);
        int4   q = *(reinterpret_cast<const int4*>(m)   + tid + j * 256);
        v[j * 4 + 0] = q.x ? -1.0e9f : f.x;
        v[j * 4 + 1] = q.y ? -1.0e9f : f.y;
        v[j * 4 + 2] = q.z ? -1.0e9f : f.z;
        v[j * 4 + 3] = q.w ? -1.0e9f : f.w;
    }
    float mx = -3.0e38f;
#pragma unroll
    for (int i = 0; i < 16; ++i) mx = fmaxf(mx, v[i]);
#pragma unroll
    for (int off = 32; off; off >>= 1) mx = fmaxf(mx, __shfl_xor(mx, off, 64));
    if (lane == 0) redmax[wave] = mx;
    __syncthreads();
    mx = fmaxf(fmaxf(redmax[0], redmax[1]), fmaxf(redmax[2], redmax[3]));

    float z = 0.f;
#pragma unroll
    for (int i = 0; i < 16; ++i) {
        v[i] = exp2f((v[i] - mx) * 1.4426950408889634f);
        z += v[i];
    }
#pragma unroll
    for (int off = 32; off; off >>= 1) z += __shfl_xor(z, off, 64);
    if (lane == 0) redsum[wave] = z;
    __syncthreads();
    z = (redsum[0] + redsum[1]) + (redsum[2] + redsum[3]);
    float inv = 1.0f / z;

    unsigned short* __restrict__ arow = attn + (size_t)row * L_;
#pragma unroll
    for (int j = 0; j < 4; ++j) {
        ushort4 u;
        u.x = f2bf(v[j * 4 + 0] * inv);
        u.y = f2bf(v[j * 4 + 1] * inv);
        u.z = f2bf(v[j * 4 + 2] * inv);
        u.w = f2bf(v[j * 4 + 3] * inv);
        *(reinterpret_cast<ushort4*>(arow) + tid + j * 256) = u;
    }
}

// ==================== Kernel 3: context = attn @ mask ====================
// R1-proven structure; REP x identical passes for rocprof visibility.
__global__ __launch_bounds__(256, 1) void k_context(
    const float* __restrict__ mask, const unsigned short* __restrict__ attn,
    float* __restrict__ out) {
    __shared__ unsigned short lA[2][64 * 64];   // attn [t][l]
    __shared__ unsigned short lB[2][64 * 64];   // mask [d][l] transposed
    const int tid  = threadIdx.x;
    const int lane = tid & 63;
    const int wave = tid >> 6;
    const int wm = wave >> 1, wn = wave & 1;
    const int b  = blockIdx.y;
    const int d0 = blockIdx.x * 64;
    const float*          __restrict__ Mb = mask + (size_t)b * L_ * D_;
    const unsigned short* __restrict__ Ab = attn + (size_t)b * T_ * L_;

    f32x4 acc[2][2];
    uint4  ra[2];
    float4 rb[4];

    auto loadTiles = [&](int k0) {
#pragma unroll
        for (int s = 0; s < 2; ++s) {
            int slot = tid + s * 256;
            int r = slot >> 3, c = slot & 7;
            ra[s] = *reinterpret_cast<const uint4*>(Ab + (size_t)r * L_ + k0 + c * 8);
        }
#pragma unroll
        for (int s = 0; s < 4; ++s) {
            int slot = tid + s * 256;
            int kl = slot >> 4, c = slot & 15;
            rb[s] = *reinterpret_cast<const float4*>(Mb + (size_t)(k0 + kl) * D_ + d0 + c * 4);
        }
    };
    auto writeTiles = [&](int buf) {
#pragma unroll
        for (int s = 0; s < 2; ++s) {
            int slot = tid + s * 256;
            int r = slot >> 3, c = slot & 7;
            int off = r * 128 + swz16(r, c * 16);
            *reinterpret_cast<uint4*>(reinterpret_cast<char*>(lA[buf]) + off) = ra[s];
        }
#pragma unroll
        for (int s = 0; s < 4; ++s) {
            int slot = tid + s * 256;
            int kl = slot >> 4, c = slot & 15;
            float fv[4] = { rb[s].x, rb[s].y, rb[s].z, rb[s].w };
#pragma unroll
            for (int i = 0; i < 4; ++i) {
                int d = c * 4 + i;
                int off = d * 128 + swz16(d, kl * 2);   // transposed scalar b16 store
                *reinterpret_cast<unsigned short*>(reinterpret_cast<char*>(lB[buf]) + off) = f2bf(fv[i]);
            }
        }
    };

    const int NT = L_ / 64;
    for (int rep = 0; rep < REP; ++rep) {
#pragma unroll
        for (int mi = 0; mi < 2; ++mi)
#pragma unroll
            for (int nj = 0; nj < 2; ++nj)
                acc[mi][nj] = f32x4{0.f, 0.f, 0.f, 0.f};

        loadTiles(0);
        writeTiles(0);
        __syncthreads();
        for (int kt = 0; kt < NT; ++kt) {
            int cur = kt & 1;
            if (kt + 1 < NT) loadTiles((kt + 1) * 64);
#pragma unroll
            for (int kk = 0; kk < 2; ++kk) {
                bf8 a0 = read_frag(lA[cur], wm * 32 +      (lane & 15), kk, lane);
                bf8 a1 = read_frag(lA[cur], wm * 32 + 16 + (lane & 15), kk, lane);
                bf8 b0 = read_frag(lB[cur], wn * 32 +      (lane & 15), kk, lane);
                bf8 b1 = read_frag(lB[cur], wn * 32 + 16 + (lane & 15), kk, lane);
                acc[0][0] = __builtin_amdgcn_mfma_f32_16x16x32_bf16(a0, b0, acc[0][0], 0, 0, 0);
                acc[0][1] = __builtin_amdgcn_mfma_f32_16x16x32_bf16(a0, b1, acc[0][1], 0, 0, 0);
                acc[1][0] = __builtin_amdgcn_mfma_f32_16x16x32_bf16(a1, b0, acc[1][0], 0, 0, 0);
                acc[1][1] = __builtin_amdgcn_mfma_f32_16x16x32_bf16(a1, b1, acc[1][1], 0, 0, 0);
            }
            if (kt + 1 < NT) writeTiles(cur ^ 1);
            __syncthreads();
        }
    }

    const int rgrp = (lane >> 4) * 4;
    const int cidx = lane & 15;
#pragma unroll
    for (int mi = 0; mi < 2; ++mi)
#pragma unroll
        for (int nj = 0; nj < 2; ++nj)
#pragma unroll
            for (int r = 0; r < 4; ++r) {
                int t = wm * 32 + mi * 16 + rgrp + r;
                int d = d0 + wn * 32 + nj * 16 + cidx;
                out[((size_t)b * T_ + t) * D_ + d] = acc[mi][nj][r];
            }
}

extern "C" void kernel_launch(void* const* d_in, const int* in_sizes, int n_in,
                              void* d_out, int out_size, void* d_ws, size_t ws_size,
                              hipStream_t stream) {
    const float* mask = (const float*)d_in[0];        // [B, L, D] fp32
    const float* Q    = (const float*)d_in[1];        // [1, T, D] fp32
    const int*   am   = (const int*)d_in[2];          // [B, T, L] int (bool)
    float* out = (float*)d_out;                       // [B, T, D] fp32

    unsigned short* attn = (unsigned short*)d_ws;                             // 2 MB bf16
    unsigned short* Qbf  = (unsigned short*)((char*)d_ws + (2u << 20));       // 512 KB
    float*          scrs = (float*)((char*)d_ws + (2u << 20) + (512u << 10)); // 4 MB

    k_qprep<<<dim3(T_ * D_ / 4 / 256), 256, 0, stream>>>(Q, Qbf);
    k_scores<<<dim3(L_ / 64, B_), 256, 0, stream>>>(mask, Qbf, scrs);
    k_softmax<<<dim3(B_ * T_), 256, 0, stream>>>(scrs, am, attn);
    k_context<<<dim3(D_ / 64, B_), 256, 0, stream>>>(mask, attn, out);
}

// Round 9
// 195.890 us; speedup vs baseline: 2.4206x; 2.4206x over previous
//
#include <hip/hip_runtime.h>
#include <hip/hip_bf16.h>
#include <stdint.h>

#define B_ 4
#define T_ 64
#define L_ 4096
#define D_ 4096

using bf8   = __attribute__((ext_vector_type(8))) short;   // 8 bf16 (4 VGPRs)
using f32x4 = __attribute__((ext_vector_type(4))) float;   // MFMA accumulator

// round-to-nearest-even fp32 -> bf16 (bit pattern in ushort) — scalar path
__device__ __forceinline__ unsigned short f2bf(float f) {
    union { float f; unsigned int u; } v;
    v.f = f;
    unsigned int r = v.u + 0x7fffu + ((v.u >> 16) & 1u);
    return (unsigned short)(r >> 16);
}

// HW packed f32->bf16 RNE (no builtin on gfx950) — non-volatile so it can pipeline
__device__ __forceinline__ unsigned int cvt_pk(float lo, float hi) {
    unsigned int r;
    asm("v_cvt_pk_bf16_f32 %0, %1, %2" : "=v"(r) : "v"(lo), "v"(hi));
    return r;
}

union BF8U { bf8 v; unsigned int u[4]; };

// Fragment-order layouts (per batch for attn; global for Q):
//   chunk(i, s, lane) = (i*128 + s)*64 + lane   [16B per chunk]
//   holds rows t = 16*i + (lane&15), k-elements 32*s + (lane>>4)*8 .. +8
// A-frag load in the GEMMs = one coalesced dwordx4 at chunk*16B.

// ---------------- Kernel 0: Q fp32 -> bf16 in FRAG ORDER ----------------
__global__ __launch_bounds__(256) void k_qprep(const float* __restrict__ Q,
                                               unsigned short* __restrict__ qf) {
    int chunk = blockIdx.x * 256 + threadIdx.x;      // 32768 chunks = 128 blocks
    int lane = chunk & 63, s = (chunk >> 6) & 127, i = chunk >> 13;
    int t = 16 * i + (lane & 15), d = 32 * s + (lane >> 4) * 8;
    const float* p = Q + (size_t)t * D_ + d;
    float4 f0 = *reinterpret_cast<const float4*>(p);
    float4 f1 = *reinterpret_cast<const float4*>(p + 4);
    BF8U bb;
    bb.u[0] = cvt_pk(f0.x, f0.y); bb.u[1] = cvt_pk(f0.z, f0.w);
    bb.u[2] = cvt_pk(f1.x, f1.y); bb.u[3] = cvt_pk(f1.z, f1.w);
    *reinterpret_cast<bf8*>(qf + (size_t)chunk * 8) = bb.v;
}

// ==================== Kernel 1: scores partials = Q . mask^T ====================
// Barrier-free streaming. 2048 waves (512 blocks), 8 waves/CU.
// Wave = 16 mask rows x ALL 64 t x half of D (split-D). Mask read exactly once.
__global__ __launch_bounds__(256, 2) void k_scores(
    const float* __restrict__ mask, const unsigned short* __restrict__ qf,
    float* __restrict__ s0, float* __restrict__ s1) {
    const int tid  = threadIdx.x;
    const int lane = tid & 63;
    const int w  = blockIdx.x * 4 + (tid >> 6);
    const int lt = w & 255;            // l-tile (16 rows)
    const int b  = (w >> 8) & 3;
    const int dh = w >> 10;            // D-half
    const int lr = lane & 15, hi = lane >> 4;

    const float* __restrict__ pB =
        mask + (size_t)b * L_ * D_ + (size_t)(lt * 16 + lr) * D_ + dh * 2048 + hi * 8;
    const unsigned short* __restrict__ pA = qf + ((size_t)(dh * 64) * 64 + lane) * 8;
    const int IBLK = 128 * 64 * 8;     // shorts per i-block in frag layout

    f32x4 acc0 = {}, acc1 = {}, acc2 = {}, acc3 = {};
#pragma unroll 4
    for (int k = 0; k < 2048; k += 32) {
        float4 f0 = *reinterpret_cast<const float4*>(pB + k);
        float4 f1 = *reinterpret_cast<const float4*>(pB + k + 4);
        const int so = (k >> 5) * 64 * 8;
        bf8 a0 = *reinterpret_cast<const bf8*>(pA + so);
        bf8 a1 = *reinterpret_cast<const bf8*>(pA + IBLK + so);
        bf8 a2 = *reinterpret_cast<const bf8*>(pA + 2 * IBLK + so);
        bf8 a3 = *reinterpret_cast<const bf8*>(pA + 3 * IBLK + so);
        BF8U bb;
        bb.u[0] = cvt_pk(f0.x, f0.y); bb.u[1] = cvt_pk(f0.z, f0.w);
        bb.u[2] = cvt_pk(f1.x, f1.y); bb.u[3] = cvt_pk(f1.z, f1.w);
        acc0 = __builtin_amdgcn_mfma_f32_16x16x32_bf16(a0, bb.v, acc0, 0, 0, 0);
        acc1 = __builtin_amdgcn_mfma_f32_16x16x32_bf16(a1, bb.v, acc1, 0, 0, 0);
        acc2 = __builtin_amdgcn_mfma_f32_16x16x32_bf16(a2, bb.v, acc2, 0, 0, 0);
        acc3 = __builtin_amdgcn_mfma_f32_16x16x32_bf16(a3, bb.v, acc3, 0, 0, 0);
    }

    // C/D: col = lane&15 (= l), row = hi*4 + reg (t within 16-block)
    float* __restrict__ S = (dh ? s1 : s0) + (size_t)b * T_ * L_ + lt * 16 + lr;
#pragma unroll
    for (int r = 0; r < 4; ++r) {
        S[(size_t)(     hi * 4 + r) * L_] = acc0[r];
        S[(size_t)(16 + hi * 4 + r) * L_] = acc1[r];
        S[(size_t)(32 + hi * 4 + r) * L_] = acc2[r];
        S[(size_t)(48 + hi * 4 + r) * L_] = acc3[r];
    }
}

// ---------------- Kernel 2: softmax((p0+p1)*scale, mask) -> bf16 attn in FRAG ORDER ----------------
__global__ __launch_bounds__(256, 4) void k_softmax(
    const float* __restrict__ s0, const float* __restrict__ s1,
    const int* __restrict__ am, unsigned short* __restrict__ af) {
    const int row  = blockIdx.x;                 // b*T + t
    const int tid  = threadIdx.x;
    const int lane = tid & 63;
    const int wave = tid >> 6;
    const int b = row >> 6, t = row & 63;
    const float* __restrict__ p0 = s0 + (size_t)row * L_;
    const float* __restrict__ p1 = s1 + (size_t)row * L_;
    const int*   __restrict__ m  = am + (size_t)row * L_;
    __shared__ float redmax[4], redsum[4];

    float v[16];
#pragma unroll
    for (int j = 0; j < 4; ++j) {
        float4 a = reinterpret_cast<const float4*>(p0)[tid + j * 256];
        float4 c = reinterpret_cast<const float4*>(p1)[tid + j * 256];
        int4   q = reinterpret_cast<const int4*>(m)[tid + j * 256];
        v[j * 4 + 0] = q.x ? -1.0e9f : (a.x + c.x) * 0.015625f;
        v[j * 4 + 1] = q.y ? -1.0e9f : (a.y + c.y) * 0.015625f;
        v[j * 4 + 2] = q.z ? -1.0e9f : (a.z + c.z) * 0.015625f;
        v[j * 4 + 3] = q.w ? -1.0e9f : (a.w + c.w) * 0.015625f;
    }
    float mx = -3.0e38f;
#pragma unroll
    for (int i = 0; i < 16; ++i) mx = fmaxf(mx, v[i]);
#pragma unroll
    for (int off = 32; off; off >>= 1) mx = fmaxf(mx, __shfl_xor(mx, off, 64));
    if (lane == 0) redmax[wave] = mx;
    __syncthreads();
    mx = fmaxf(fmaxf(redmax[0], redmax[1]), fmaxf(redmax[2], redmax[3]));

    float z = 0.f;
#pragma unroll
    for (int i = 0; i < 16; ++i) {
        v[i] = exp2f((v[i] - mx) * 1.4426950408889634f);
        z += v[i];
    }
#pragma unroll
    for (int off = 32; off; off >>= 1) z += __shfl_xor(z, off, 64);
    if (lane == 0) redsum[wave] = z;
    __syncthreads();
    z = (redsum[0] + redsum[1]) + (redsum[2] + redsum[3]);
    float inv = 1.0f / z;

    // frag-order write: row t contributes lane slot (t&15) + 16*hi for every step s
    const int i  = t >> 4;
    const int lrp = t & 15;
    unsigned short* __restrict__ ab = af + (size_t)b * T_ * L_;
#pragma unroll
    for (int j = 0; j < 4; ++j) {
        int l0j  = 4 * (tid + j * 256);          // first l of this thread's 4 values
        int c    = l0j >> 3;                     // 8-element chunk index
        int half = (l0j >> 2) & 1;               // which 8B half of the 16B chunk
        int s    = c >> 2;
        int h2   = c & 3;
        size_t off = ((size_t)(i * 128 + s) * 64 + (lrp + 16 * h2)) * 8 + half * 4;
        ushort4 u;
        u.x = f2bf(v[j * 4 + 0] * inv);
        u.y = f2bf(v[j * 4 + 1] * inv);
        u.z = f2bf(v[j * 4 + 2] * inv);
        u.w = f2bf(v[j * 4 + 3] * inv);
        *reinterpret_cast<ushort4*>(ab + off) = u;
    }
}

// ==================== Kernel 3: context = attn @ mask ====================
// Barrier-free streaming. 1024 waves (256 blocks), 4 waves/CU.
// Wave = 16 d-cols x ALL 64 t x full L. Mask column slice read once (L3-warm).
__global__ __launch_bounds__(256, 2) void k_context(
    const float* __restrict__ mask, const unsigned short* __restrict__ af,
    float* __restrict__ out) {
    const int tid  = threadIdx.x;
    const int lane = tid & 63;
    const int w  = blockIdx.x * 4 + (tid >> 6);  // 0..1023
    const int dt = w & 255;
    const int b  = w >> 8;
    const int d0 = dt * 16;
    const int lr = lane & 15, hi = lane >> 4;

    const unsigned short* __restrict__ pA = af + (size_t)b * T_ * L_ + (size_t)lane * 8;
    const float* __restrict__ pB =
        mask + (size_t)b * L_ * D_ + (size_t)(hi * 8) * D_ + d0 + lr;
    const int IBLK = 128 * 64 * 8;

    f32x4 acc0 = {}, acc1 = {}, acc2 = {}, acc3 = {};
#pragma unroll 2
    for (int k = 0; k < L_; k += 32) {
        const float* __restrict__ pb = pB + (size_t)k * D_;
        float b0 = pb[0];
        float b1 = pb[(size_t)1 * D_];
        float b2 = pb[(size_t)2 * D_];
        float b3 = pb[(size_t)3 * D_];
        float b4 = pb[(size_t)4 * D_];
        float b5 = pb[(size_t)5 * D_];
        float b6 = pb[(size_t)6 * D_];
        float b7 = pb[(size_t)7 * D_];
        const int so = (k >> 5) * 64 * 8;
        bf8 a0 = *reinterpret_cast<const bf8*>(pA + so);
        bf8 a1 = *reinterpret_cast<const bf8*>(pA + IBLK + so);
        bf8 a2 = *reinterpret_cast<const bf8*>(pA + 2 * IBLK + so);
        bf8 a3 = *reinterpret_cast<const bf8*>(pA + 3 * IBLK + so);
        BF8U bb;
        bb.u[0] = cvt_pk(b0, b1); bb.u[1] = cvt_pk(b2, b3);
        bb.u[2] = cvt_pk(b4, b5); bb.u[3] = cvt_pk(b6, b7);
        acc0 = __builtin_amdgcn_mfma_f32_16x16x32_bf16(a0, bb.v, acc0, 0, 0, 0);
        acc1 = __builtin_amdgcn_mfma_f32_16x16x32_bf16(a1, bb.v, acc1, 0, 0, 0);
        acc2 = __builtin_amdgcn_mfma_f32_16x16x32_bf16(a2, bb.v, acc2, 0, 0, 0);
        acc3 = __builtin_amdgcn_mfma_f32_16x16x32_bf16(a3, bb.v, acc3, 0, 0, 0);
    }

    float* __restrict__ O = out + (size_t)b * T_ * D_ + d0 + lr;
#pragma unroll
    for (int r = 0; r < 4; ++r) {
        O[(size_t)(     hi * 4 + r) * D_] = acc0[r];
        O[(size_t)(16 + hi * 4 + r) * D_] = acc1[r];
        O[(size_t)(32 + hi * 4 + r) * D_] = acc2[r];
        O[(size_t)(48 + hi * 4 + r) * D_] = acc3[r];
    }
}

extern "C" void kernel_launch(void* const* d_in, const int* in_sizes, int n_in,
                              void* d_out, int out_size, void* d_ws, size_t ws_size,
                              hipStream_t stream) {
    const float* mask = (const float*)d_in[0];        // [B, L, D] fp32
    const float* Q    = (const float*)d_in[1];        // [1, T, D] fp32
    const int*   am   = (const int*)d_in[2];          // [B, T, L] int (bool)
    float* out = (float*)d_out;                       // [B, T, D] fp32

    unsigned short* af = (unsigned short*)d_ws;                               // attn frag-order, 2 MB
    unsigned short* qf = (unsigned short*)((char*)d_ws + (2u << 20));         // Q frag-order, 512 KB
    float*          s0 = (float*)((char*)d_ws + (2u << 20) + (512u << 10));   // scores partial 0, 4 MB
    float*          s1 = out;                                                 // scores partial 1 (overwritten later)

    k_qprep  <<<dim3(128), 256, 0, stream>>>(Q, qf);
    k_scores <<<dim3(512), 256, 0, stream>>>(mask, qf, s0, s1);
    k_softmax<<<dim3(B_ * T_), 256, 0, stream>>>(s0, s1, am, af);
    k_context<<<dim3(256), 256, 0, stream>>>(mask, af, out);
}